// Round 1
// baseline (615.676 us; speedup 1.0000x reference)
//
#include <hip/hip_runtime.h>
#include <hip/hip_bf16.h>

#define NN 20000
#define NE 320000
#define DD 256

typedef __attribute__((ext_vector_type(8))) short bf16x8;   // 8 bf16 = 4 VGPR (MFMA A/B frag)
typedef __attribute__((ext_vector_type(4))) float f32x4;    // MFMA C/D frag
typedef __attribute__((ext_vector_type(4))) int   int4v;    // 16B staging chunk
typedef __attribute__((ext_vector_type(4))) float float4v;

__device__ __forceinline__ unsigned short f2bf(float f) {
    union { float f; unsigned u; } v; v.f = f;
    unsigned r = v.u + 0x7fffu + ((v.u >> 16) & 1u);   // RNE
    return (unsigned short)(r >> 16);
}
__device__ __forceinline__ float bf2f(unsigned short h) {
    union { unsigned u; float f; } v; v.u = ((unsigned)h) << 16;
    return v.f;
}

// ---------------- prologue kernels ----------------

// Wt[l][n][k] = W[l][k][n], cast to bf16 (B^T layout for MFMA B staging)
__global__ void tw_kernel(const float* __restrict__ W, unsigned short* __restrict__ Wt) {
    int id = blockIdx.x * 256 + threadIdx.x;          // 5*256*256 = 327680
    int l = id >> 16, rem = id & 65535;
    int k = rem >> 8, n = rem & 255;
    Wt[l * 65536 + n * 256 + k] = f2bf(W[id]);
}

__global__ void cast_kernel(const float* __restrict__ in, unsigned short* __restrict__ out, int n) {
    int i = (blockIdx.x * blockDim.x + threadIdx.x) * 4;
    if (i >= n) return;
    float4v v = *reinterpret_cast<const float4v*>(in + i);
    uint2 o;
    o.x = (unsigned)f2bf(v.x) | ((unsigned)f2bf(v.y) << 16);
    o.y = (unsigned)f2bf(v.z) | ((unsigned)f2bf(v.w) << 16);
    *reinterpret_cast<uint2*>(out + i) = o;
}

// ---------------- CSR build (once per launch) ----------------

__global__ void hist_kernel(const int* __restrict__ dst, int* __restrict__ deg) {
    int e = blockIdx.x * 256 + threadIdx.x;
    if (e < NE) atomicAdd(&deg[dst[e]], 1);
}

__global__ __launch_bounds__(1024) void scan_kernel(const int* __restrict__ deg, int* __restrict__ base) {
    __shared__ int part[1024];
    const int t = threadIdx.x;
    const int CH = 20;                                 // 1024*20 >= NN
    int start = t * CH;
    int s = 0;
    for (int i = 0; i < CH; ++i) { int idx = start + i; if (idx < NN) s += deg[idx]; }
    part[t] = s; __syncthreads();
    for (int off = 1; off < 1024; off <<= 1) {
        int v = (t >= off) ? part[t - off] : 0;
        __syncthreads();
        part[t] += v;
        __syncthreads();
    }
    int run = (t == 0) ? 0 : part[t - 1];
    for (int i = 0; i < CH; ++i) {
        int idx = start + i;
        if (idx < NN) { base[idx] = run; run += deg[idx]; }
    }
    if (t == 1023) base[NN] = run;                     // == NE
}

__global__ void fill_kernel(const int* __restrict__ src, const int* __restrict__ dst,
                            const float* __restrict__ attr, const int* __restrict__ base,
                            int* __restrict__ cursor, int* __restrict__ ssrc,
                            float* __restrict__ sattr) {
    int e = blockIdx.x * 256 + threadIdx.x;
    if (e >= NE) return;
    int d = dst[e];
    int pos = base[d] + atomicAdd(&cursor[d], 1);
    ssrc[pos] = src[e];
    sattr[pos] = attr[e];
}

// ---------------- GEMM: m_bf = h_bf @ W (Wt is [N][K] bf16) ----------------
// BM=128, BN=64, BK=64; 4 waves (2x2), wave tile 64x32, mfma 16x16x32 bf16.
__global__ __launch_bounds__(256) void gemm_m_kernel(const unsigned short* __restrict__ A,
                                                     const unsigned short* __restrict__ Bt,
                                                     unsigned short* __restrict__ C) {
    __shared__ __align__(16) unsigned short As[128 * 64];
    __shared__ __align__(16) unsigned short Bs[64 * 64];
    const int t = threadIdx.x;
    const int lane = t & 63;
    const int w = t >> 6;
    const int wr = w >> 1, wc = w & 1;
    const int m0 = blockIdx.y * 128;
    const int n0 = blockIdx.x * 64;

    f32x4 acc[4][2];
    const f32x4 z4 = {0.f, 0.f, 0.f, 0.f};
    for (int i = 0; i < 4; ++i) for (int j = 0; j < 2; ++j) acc[i][j] = z4;

    for (int kt = 0; kt < 4; ++kt) {
        const int k0 = kt * 64;
#pragma unroll
        for (int rnd = 0; rnd < 4; ++rnd) {            // A: 128 rows x 8 slots
            int c = t + rnd * 256;
            int row = c >> 3, slot = c & 7;
            int4v v = {0, 0, 0, 0};
            int gr = m0 + row;
            if (gr < NN) v = *reinterpret_cast<const int4v*>(A + gr * 256 + k0 + slot * 8);
            *reinterpret_cast<int4v*>(&As[row * 64 + ((slot ^ (row & 7)) << 3)]) = v;
        }
#pragma unroll
        for (int rnd = 0; rnd < 2; ++rnd) {            // B: 64 rows x 8 slots
            int c = t + rnd * 256;
            int row = c >> 3, slot = c & 7;
            int4v v = *reinterpret_cast<const int4v*>(Bt + (n0 + row) * 256 + k0 + slot * 8);
            *reinterpret_cast<int4v*>(&Bs[row * 64 + ((slot ^ (row & 7)) << 3)]) = v;
        }
        __syncthreads();
#pragma unroll
        for (int ks = 0; ks < 2; ++ks) {
            const int slot = ks * 4 + (lane >> 4);
            bf16x8 a[4], b[2];
#pragma unroll
            for (int mi = 0; mi < 4; ++mi) {
                int row = wr * 64 + mi * 16 + (lane & 15);
                a[mi] = *reinterpret_cast<const bf16x8*>(&As[row * 64 + ((slot ^ (row & 7)) << 3)]);
            }
#pragma unroll
            for (int ni = 0; ni < 2; ++ni) {
                int row = wc * 32 + ni * 16 + (lane & 15);
                b[ni] = *reinterpret_cast<const bf16x8*>(&Bs[row * 64 + ((slot ^ (row & 7)) << 3)]);
            }
#pragma unroll
            for (int mi = 0; mi < 4; ++mi)
#pragma unroll
                for (int ni = 0; ni < 2; ++ni)
                    acc[mi][ni] = __builtin_amdgcn_mfma_f32_16x16x32_bf16(a[mi], b[ni], acc[mi][ni], 0, 0, 0);
        }
        __syncthreads();
    }
#pragma unroll
    for (int mi = 0; mi < 4; ++mi)
#pragma unroll
        for (int ni = 0; ni < 2; ++ni)
#pragma unroll
            for (int r = 0; r < 4; ++r) {
                int grow = m0 + wr * 64 + mi * 16 + (lane >> 4) * 4 + r;
                int gcol = n0 + wc * 32 + ni * 16 + (lane & 15);
                if (grow < NN) C[grow * 256 + gcol] = f2bf(acc[mi][ni][r]);
            }
}

// ---------------- aggregation: agg_bf[n] = sum_{e: dst=n} attr[e]*m_bf[src[e]] ----------------
// one wave per node, lane owns 4 contiguous d's; CSR-sorted src/attr, no atomics.
__global__ __launch_bounds__(256) void gather_agg_kernel(const unsigned short* __restrict__ Mbf,
                                                         const int* __restrict__ base,
                                                         const int* __restrict__ ssrc,
                                                         const float* __restrict__ sattr,
                                                         unsigned short* __restrict__ AggBf) {
    int node = blockIdx.x * 4 + (threadIdx.x >> 6);
    if (node >= NN) return;
    int lane = threadIdx.x & 63;
    int b0 = base[node], b1 = base[node + 1];
    float a0 = 0.f, a1 = 0.f, a2 = 0.f, a3 = 0.f;
    for (int p = b0; p < b1; ++p) {
        int s = ssrc[p];
        float a = sattr[p];
        uint2 v = *reinterpret_cast<const uint2*>(Mbf + s * 256 + lane * 4);
        a0 += a * bf2f((unsigned short)(v.x & 0xffff));
        a1 += a * bf2f((unsigned short)(v.x >> 16));
        a2 += a * bf2f((unsigned short)(v.y & 0xffff));
        a3 += a * bf2f((unsigned short)(v.y >> 16));
    }
    uint2 o;
    o.x = (unsigned)f2bf(a0) | ((unsigned)f2bf(a1) << 16);
    o.y = (unsigned)f2bf(a2) | ((unsigned)f2bf(a3) << 16);
    *reinterpret_cast<uint2*>(AggBf + node * 256 + lane * 4) = o;
}

// ---------------- fused GRU: gi/gh GEMMs + gates, no gi/gh buffers ----------------
// block: BM=64 rows x BD=64 d-strip; 4 waves 2x2 over 32x32 subtiles.
// 4 accumulator sets: R (K=512: agg@Wir^T + h@Whr^T), Z (K=512), IN (K=256), HN (K=256).
__global__ __launch_bounds__(256) void gru_kernel(const unsigned short* __restrict__ Abf,
                                                  const unsigned short* __restrict__ Hbf,
                                                  const unsigned short* __restrict__ Wih,
                                                  const unsigned short* __restrict__ Whh,
                                                  const float* __restrict__ b_ih,
                                                  const float* __restrict__ b_hh,
                                                  const float* __restrict__ h_in,
                                                  float* __restrict__ h_out,
                                                  unsigned short* __restrict__ Hbf_out) {
    __shared__ __align__(16) unsigned short A1s[64 * 64];
    __shared__ __align__(16) unsigned short A2s[64 * 64];
    __shared__ __align__(16) unsigned short Bi[3][64 * 64];
    __shared__ __align__(16) unsigned short Bh[3][64 * 64];
    const int t = threadIdx.x;
    const int lane = t & 63;
    const int w = t >> 6;
    const int wr = w >> 1, wc = w & 1;
    const int m0 = blockIdx.y * 64;
    const int d0 = blockIdx.x * 64;

    f32x4 aR[2][2], aZ[2][2], aN[2][2], aH[2][2];
    const f32x4 z4 = {0.f, 0.f, 0.f, 0.f};
    for (int i = 0; i < 2; ++i) for (int j = 0; j < 2; ++j) { aR[i][j] = z4; aZ[i][j] = z4; aN[i][j] = z4; aH[i][j] = z4; }

    for (int kt = 0; kt < 4; ++kt) {
        const int k0 = kt * 64;
#pragma unroll
        for (int rnd = 0; rnd < 2; ++rnd) {            // A1/A2: 64 rows x 8 slots each
            int c = t + rnd * 256;
            int row = c >> 3, slot = c & 7;
            int lofs = row * 64 + ((slot ^ (row & 7)) << 3);
            int gr = m0 + row;
            int4v v1 = {0, 0, 0, 0}, v2 = {0, 0, 0, 0};
            if (gr < NN) {
                v1 = *reinterpret_cast<const int4v*>(Abf + gr * 256 + k0 + slot * 8);
                v2 = *reinterpret_cast<const int4v*>(Hbf + gr * 256 + k0 + slot * 8);
            }
            *reinterpret_cast<int4v*>(&A1s[lofs]) = v1;
            *reinterpret_cast<int4v*>(&A2s[lofs]) = v2;
        }
#pragma unroll
        for (int g = 0; g < 3; ++g)
#pragma unroll
            for (int rnd = 0; rnd < 2; ++rnd) {        // 6 weight strips [64][64]
                int c = t + rnd * 256;
                int row = c >> 3, slot = c & 7;
                int lofs = row * 64 + ((slot ^ (row & 7)) << 3);
                int gofs = (g * 256 + d0 + row) * 256 + k0 + slot * 8;
                *reinterpret_cast<int4v*>(&Bi[g][lofs]) = *reinterpret_cast<const int4v*>(Wih + gofs);
                *reinterpret_cast<int4v*>(&Bh[g][lofs]) = *reinterpret_cast<const int4v*>(Whh + gofs);
            }
        __syncthreads();
#pragma unroll
        for (int ks = 0; ks < 2; ++ks) {
            const int slot = ks * 4 + (lane >> 4);
            bf16x8 a1[2], a2[2];
#pragma unroll
            for (int mi = 0; mi < 2; ++mi) {
                int row = wr * 32 + mi * 16 + (lane & 15);
                int ofs = row * 64 + ((slot ^ (row & 7)) << 3);
                a1[mi] = *reinterpret_cast<const bf16x8*>(&A1s[ofs]);
                a2[mi] = *reinterpret_cast<const bf16x8*>(&A2s[ofs]);
            }
            bf16x8 bi_[3][2], bh_[3][2];
#pragma unroll
            for (int ni = 0; ni < 2; ++ni) {
                int row = wc * 32 + ni * 16 + (lane & 15);
                int ofs = row * 64 + ((slot ^ (row & 7)) << 3);
#pragma unroll
                for (int g = 0; g < 3; ++g) {
                    bi_[g][ni] = *reinterpret_cast<const bf16x8*>(&Bi[g][ofs]);
                    bh_[g][ni] = *reinterpret_cast<const bf16x8*>(&Bh[g][ofs]);
                }
            }
#pragma unroll
            for (int mi = 0; mi < 2; ++mi)
#pragma unroll
                for (int ni = 0; ni < 2; ++ni) {
                    aR[mi][ni] = __builtin_amdgcn_mfma_f32_16x16x32_bf16(a1[mi], bi_[0][ni], aR[mi][ni], 0, 0, 0);
                    aR[mi][ni] = __builtin_amdgcn_mfma_f32_16x16x32_bf16(a2[mi], bh_[0][ni], aR[mi][ni], 0, 0, 0);
                    aZ[mi][ni] = __builtin_amdgcn_mfma_f32_16x16x32_bf16(a1[mi], bi_[1][ni], aZ[mi][ni], 0, 0, 0);
                    aZ[mi][ni] = __builtin_amdgcn_mfma_f32_16x16x32_bf16(a2[mi], bh_[1][ni], aZ[mi][ni], 0, 0, 0);
                    aN[mi][ni] = __builtin_amdgcn_mfma_f32_16x16x32_bf16(a1[mi], bi_[2][ni], aN[mi][ni], 0, 0, 0);
                    aH[mi][ni] = __builtin_amdgcn_mfma_f32_16x16x32_bf16(a2[mi], bh_[2][ni], aH[mi][ni], 0, 0, 0);
                }
        }
        __syncthreads();
    }
#pragma unroll
    for (int mi = 0; mi < 2; ++mi)
#pragma unroll
        for (int ni = 0; ni < 2; ++ni)
#pragma unroll
            for (int r = 0; r < 4; ++r) {
                int grow = m0 + wr * 32 + mi * 16 + (lane >> 4) * 4 + r;
                if (grow >= NN) continue;
                int gcol = d0 + wc * 32 + ni * 16 + (lane & 15);
                float rpre = aR[mi][ni][r] + b_ih[gcol] + b_hh[gcol];
                float zpre = aZ[mi][ni][r] + b_ih[256 + gcol] + b_hh[256 + gcol];
                float rr = 1.f / (1.f + __expf(-rpre));
                float zz = 1.f / (1.f + __expf(-zpre));
                float nn = tanhf(aN[mi][ni][r] + b_ih[512 + gcol] + rr * (aH[mi][ni][r] + b_hh[512 + gcol]));
                float hp = h_in[grow * 256 + gcol];
                float hv = (1.f - zz) * nn + zz * hp;
                h_out[grow * 256 + gcol] = hv;
                Hbf_out[grow * 256 + gcol] = f2bf(hv);
            }
}

// ---------------- launch ----------------

extern "C" void kernel_launch(void* const* d_in, const int* in_sizes, int n_in,
                              void* d_out, int out_size, void* d_ws, size_t ws_size,
                              hipStream_t stream) {
    const float* x     = (const float*)d_in[0];
    const int*   eidx  = (const int*)d_in[1];
    const float* eattr = (const float*)d_in[2];
    const float* W     = (const float*)d_in[3];
    const float* wih   = (const float*)d_in[4];
    const float* whh   = (const float*)d_in[5];
    const float* bih   = (const float*)d_in[6];
    const float* bhh   = (const float*)d_in[7];
    float* out = (float*)d_out;
    const int* esrc = eidx;
    const int* edst = eidx + NE;

    char* p = (char*)d_ws;
    auto alloc = [&](size_t bytes) -> char* {
        char* r = p; p += (bytes + 255) & ~(size_t)255; return r;
    };
    unsigned short* hbfA  = (unsigned short*)alloc((size_t)NN * DD * 2);
    unsigned short* hbfB  = (unsigned short*)alloc((size_t)NN * DD * 2);
    unsigned short* mbf   = (unsigned short*)alloc((size_t)NN * DD * 2);
    unsigned short* aggbf = (unsigned short*)alloc((size_t)NN * DD * 2);
    unsigned short* Wt    = (unsigned short*)alloc((size_t)5 * DD * DD * 2);
    unsigned short* wihb  = (unsigned short*)alloc((size_t)768 * DD * 2);
    unsigned short* whhb  = (unsigned short*)alloc((size_t)768 * DD * 2);
    int*   deg    = (int*)alloc((size_t)NN * 4);
    int*   basep  = (int*)alloc((size_t)(NN + 1) * 4);
    int*   cursor = (int*)alloc((size_t)NN * 4);
    int*   ssrc   = (int*)alloc((size_t)NE * 4);
    float* sattr  = (float*)alloc((size_t)NE * 4);

    hipMemsetAsync(deg, 0, (size_t)NN * 4, stream);
    hipMemsetAsync(cursor, 0, (size_t)NN * 4, stream);

    tw_kernel<<<1280, 256, 0, stream>>>(W, Wt);
    cast_kernel<<<192, 256, 0, stream>>>(wih, wihb, 768 * DD);
    cast_kernel<<<192, 256, 0, stream>>>(whh, whhb, 768 * DD);
    cast_kernel<<<5000, 256, 0, stream>>>(x, hbfA, NN * DD);
    hist_kernel<<<1250, 256, 0, stream>>>(edst, deg);
    scan_kernel<<<1, 1024, 0, stream>>>(deg, basep);
    fill_kernel<<<1250, 256, 0, stream>>>(esrc, edst, eattr, basep, cursor, ssrc, sattr);

    unsigned short* hb_cur = hbfA;
    unsigned short* hb_nxt = hbfB;
    const float* h_in = x;
    for (int l = 0; l < 5; ++l) {
        gemm_m_kernel<<<dim3(4, 157), 256, 0, stream>>>(hb_cur, Wt + (size_t)l * DD * DD, mbf);
        gather_agg_kernel<<<5000, 256, 0, stream>>>(mbf, basep, ssrc, sattr, aggbf);
        gru_kernel<<<dim3(4, 313), 256, 0, stream>>>(aggbf, hb_cur, wihb, whhb, bih, bhh,
                                                     h_in, out, hb_nxt);
        h_in = out;
        unsigned short* tmp = hb_cur; hb_cur = hb_nxt; hb_nxt = tmp;
    }
}